// Round 1
// baseline (289.951 us; speedup 1.0000x reference)
//
#include <hip/hip_runtime.h>
#include <math.h>

#define NCLS 19
#define NBATCH 4
#define HH 512
#define WW 512
#define PHD 129
#define PWD 129
#define PP (PHD*PWD)          // 16641
#define NC (NBATCH*NCLS)      // 76
#define KPOS 16129.0          // 127*127
#define NSTRIP 8
#define GS 361                // gram stride per (n,c): full 19x19, upper triangle used
#define POS_ALPHA 5e-4

// ---------------------------------------------------------------------------
// Kernel 1: fused BCE + valid-count + avg-pool(4,4,pad2) of probs and onehot.
// One thread per pooled cell (n,c,ph,pw); pooled windows partition the input,
// so each (pixel,channel) is visited exactly once -> BCE sum is exact.
// ---------------------------------------------------------------------------
__global__ __launch_bounds__(256) void k_bce_pool(
    const float* __restrict__ logits,
    const int*   __restrict__ labels,
    float*  __restrict__ pla,
    float*  __restrict__ ppr,
    double* __restrict__ accum)   // [0]=bce_sum [1]=valid_pixels [2]=rmi
{
    int idx = blockIdx.x*blockDim.x + threadIdx.x;
    double bce  = 0.0;
    double vcnt = 0.0;
    if (idx < NC*PP) {
        int nc  = idx / PP;
        int n   = nc / NCLS;
        int c   = nc % NCLS;
        int rem = idx - nc*PP;
        int ph  = rem / PWD;
        int pw  = rem - ph*PWD;
        int r0 = 4*ph - 2, c0 = 4*pw - 2;
        int rlo = max(r0, 0), rhi = min(r0 + 4, HH);
        int clo = max(c0, 0), chi = min(c0 + 4, WW);
        const float* lg = logits + ((size_t)n*NCLS + c)*((size_t)HH*WW);
        const int*   lb = labels + (size_t)n*((size_t)HH*WW);
        float psum  = 0.f;
        int   lasum = 0;
        int   vc    = 0;
        for (int r = rlo; r < rhi; ++r) {
            for (int cl = clo; cl < chi; ++cl) {
                int   lab = lb[r*WW + cl];
                float x   = lg[r*WW + cl];
                psum += 1e-6f;                 // CLP_MIN added for every in-image pixel
                if (lab < NCLS) {
                    float t = (lab == c) ? 1.f : 0.f;
                    lasum += (lab == c);
                    float ax = fabsf(x);
                    bce += (double)(fmaxf(x, 0.f) - x*t + log1pf(expf(-ax)));
                    psum += 1.f/(1.f + expf(-x));
                    vc++;
                }
            }
        }
        pla[idx] = (float)lasum * 0.0625f;
        ppr[idx] = psum * 0.0625f;             // count_include_pad: /16 always
        if (c == 0) vcnt = (double)vc;         // each pixel counted once (c==0 windows partition)
    }
    // block reduction (4 waves)
    for (int off = 32; off > 0; off >>= 1) {
        bce  += __shfl_down(bce,  off);
        vcnt += __shfl_down(vcnt, off);
    }
    __shared__ double sb[4], sv[4];
    int wid = threadIdx.x >> 6, lane = threadIdx.x & 63;
    if (lane == 0) { sb[wid] = bce; sv[wid] = vcnt; }
    __syncthreads();
    if (threadIdx.x == 0) {
        atomicAdd(&accum[0], sb[0]+sb[1]+sb[2]+sb[3]);
        atomicAdd(&accum[1], sv[0]+sv[1]+sv[2]+sv[3]);
    }
}

// ---------------------------------------------------------------------------
// Kernel 2: Gram matrix G = W W^T, W = [la views 0..8; pr views 0..8; ones]
// (19 x 16129 per (n,c)). Upper triangle incl. ones-column = all covariance
// sums + view sums. One wave handles G-rows (D0, D0+1); lanes stride j ->
// conflict-free LDS, static-indexed fp64 accumulators via template.
// ---------------------------------------------------------------------------
template<int D0>
__device__ __forceinline__ void row_pair(const float* sla, const float* spr,
                                         int ni, double* __restrict__ g)
{
    constexpr int NV  = 18 - D0;   // values W_{D0}..W_{17}
    constexpr int NA  = 19 - D0;   // row D0 accs: pairs e=D0..17 + ones-sum
    constexpr int NBB = 18 - D0;   // row D0+1 accs
    double accA[NA];
    double accB[NBB];
    #pragma unroll
    for (int k = 0; k < NA;  k++) accA[k] = 0.0;
    #pragma unroll
    for (int k = 0; k < NBB; k++) accB[k] = 0.0;
    int lane = threadIdx.x & 63;
    for (int i = 0; i < ni; i++) {
        for (int j = lane; j < 127; j += 64) {
            double v[NV];
            #pragma unroll
            for (int k = 0; k < NV; k++) {
                int e = D0 + k;
                const float* buf = (e < 9) ? sla : spr;
                int er = (e < 9) ? e : e - 9;
                v[k] = (double)buf[(i + er/3)*129 + j + (er % 3)];
            }
            double vD  = v[0];
            double vD1 = v[1];
            #pragma unroll
            for (int k = 0; k < NV; k++) accA[k] += vD * v[k];
            accA[NV] += vD;
            #pragma unroll
            for (int k = 1; k < NV; k++) accB[k-1] += vD1 * v[k];
            accB[NV-1] += vD1;
        }
    }
    #pragma unroll
    for (int k = 0; k < NA; k++) {
        double a = accA[k];
        for (int off = 32; off > 0; off >>= 1) a += __shfl_down(a, off);
        if (lane == 0) atomicAdd(&g[D0*19 + D0 + k], a);
    }
    #pragma unroll
    for (int k = 0; k < NBB; k++) {
        double a = accB[k];
        for (int off = 32; off > 0; off >>= 1) a += __shfl_down(a, off);
        if (lane == 0) atomicAdd(&g[(D0+1)*19 + (D0+1) + k], a);
    }
}

__global__ __launch_bounds__(192) void k_gram(
    const float* __restrict__ pla,
    const float* __restrict__ ppr,
    double* __restrict__ grams)
{
    __shared__ float sla[18*129];
    __shared__ float spr[18*129];
    int bid = blockIdx.x;
    int nc  = bid / (NSTRIP*3);
    int rem = bid % (NSTRIP*3);
    int s   = rem / 3;
    int rb  = rem % 3;
    int i0  = s*16;
    int ni  = min(16, 127 - i0);
    int rows = ni + 2;
    const float* gla = pla + (size_t)nc*PP + (size_t)i0*PWD;
    const float* gpr = ppr + (size_t)nc*PP + (size_t)i0*PWD;
    for (int t = threadIdx.x; t < rows*129; t += 192) {
        sla[t] = gla[t];
        spr[t] = gpr[t];
    }
    __syncthreads();
    int w  = threadIdx.x >> 6;        // wave 0..2
    int D0 = 2*(rb*3 + w);            // 0,2,...,16
    double* g = grams + (size_t)nc*GS;
    switch (D0) {
        case 0:  row_pair<0 >(sla, spr, ni, g); break;
        case 2:  row_pair<2 >(sla, spr, ni, g); break;
        case 4:  row_pair<4 >(sla, spr, ni, g); break;
        case 6:  row_pair<6 >(sla, spr, ni, g); break;
        case 8:  row_pair<8 >(sla, spr, ni, g); break;
        case 10: row_pair<10>(sla, spr, ni, g); break;
        case 12: row_pair<12>(sla, spr, ni, g); break;
        case 14: row_pair<14>(sla, spr, ni, g); break;
        case 16: row_pair<16>(sla, spr, ni, g); break;
    }
}

// ---------------------------------------------------------------------------
// Kernel 3: per-(n,c) 9x9 fp64 linear algebra.
// appro_var = la_cov - M P^-1 M^T with P = pr_cov + aI: chol(P)=LL^T,
// Y = L^-1 M^T  ->  M P^-1 M^T = Y^T Y. Then chol(appro_var + aI), logdet.
// ---------------------------------------------------------------------------
__global__ __launch_bounds__(128) void k_solve(
    const double* __restrict__ grams,
    double* __restrict__ accum)
{
    int nc = blockIdx.x;
    const double* g = grams + (size_t)nc*GS;
    __shared__ double P[81], M[81], A[81], Y[81], mla[9], mpr[9];
    int t = threadIdx.x;
    if (t < 9) {
        mla[t] = g[t*19 + 18]     / KPOS;
        mpr[t] = g[(9+t)*19 + 18] / KPOS;
    }
    __syncthreads();
    if (t < 81) {
        int d = t/9, e = t - 9*(t/9);
        double Gll = (d <= e) ? g[d*19 + e]         : g[e*19 + d];
        double Gpp = (d <= e) ? g[(9+d)*19 + 9+e]   : g[(9+e)*19 + 9+d];
        double Glp = g[d*19 + 9 + e];   // la row d (<9) vs pr row 9+e: always upper
        A[t] = Gll - KPOS*mla[d]*mla[e];                                // la_cov
        P[t] = Gpp - KPOS*mpr[d]*mpr[e] + ((d == e) ? POS_ALPHA : 0.0); // pr_cov + aI
        M[t] = Glp - KPOS*mla[d]*mpr[e];                                // la_pr
    }
    __syncthreads();
    // Cholesky of P (lower, in place)
    for (int k = 0; k < 9; k++) {
        if (t == 0) P[k*9+k] = sqrt(P[k*9+k]);
        __syncthreads();
        if (t > k && t < 9) P[t*9+k] /= P[k*9+k];
        __syncthreads();
        if (t < 81) {
            int i = t/9, j = t - 9*(t/9);
            if (i > k && j > k && j <= i) P[i*9+j] -= P[i*9+k]*P[j*9+k];
        }
        __syncthreads();
    }
    // forward solve: column t of Y = L^-1 M^T  (M^T[i][t] = M[t][i])
    if (t < 9) {
        double y[9];
        #pragma unroll
        for (int i = 0; i < 9; i++) {
            double sY = M[t*9 + i];
            #pragma unroll
            for (int m2 = 0; m2 < i; m2++) sY -= P[i*9+m2]*y[m2];
            y[i] = sY / P[i*9+i];
        }
        #pragma unroll
        for (int i = 0; i < 9; i++) Y[i*9 + t] = y[i];
    }
    __syncthreads();
    if (t < 81) {
        int d = t/9, e = t - 9*(t/9);
        double sY = 0.0;
        #pragma unroll
        for (int k = 0; k < 9; k++) sY += Y[k*9+d]*Y[k*9+e];
        A[t] = A[t] - sY + ((d == e) ? POS_ALPHA : 0.0);
    }
    __syncthreads();
    // Cholesky of appro_var + aI
    for (int k = 0; k < 9; k++) {
        if (t == 0) A[k*9+k] = sqrt(A[k*9+k]);
        __syncthreads();
        if (t > k && t < 9) A[t*9+k] /= A[k*9+k];
        __syncthreads();
        if (t < 81) {
            int i = t/9, j = t - 9*(t/9);
            if (i > k && j > k && j <= i) A[i*9+j] -= A[i*9+k]*A[j*9+k];
        }
        __syncthreads();
    }
    if (t == 0) {
        double ld = 0.0;
        for (int k = 0; k < 9; k++) ld += log(A[k*9+k]);
        // rmi contribution: 0.5*logdet / (N * HALF_D) = ld / 36
        atomicAdd(&accum[2], ld * (1.0/36.0));
    }
}

__global__ void k_final(const double* __restrict__ accum, float* __restrict__ out)
{
    if (threadIdx.x == 0 && blockIdx.x == 0) {
        double bce = accum[0] / (accum[1] + 1.0);
        out[0] = (float)(0.5*bce + 0.5*accum[2]);   // LAMBDA = 0.5
    }
}

// ---------------------------------------------------------------------------
extern "C" void kernel_launch(void* const* d_in, const int* in_sizes, int n_in,
                              void* d_out, int out_size, void* d_ws, size_t ws_size,
                              hipStream_t stream)
{
    const float* logits = (const float*)d_in[0];
    const int*   labels = (const int*)d_in[1];
    float* out = (float*)d_out;

    float*  pla   = (float*)d_ws;                       // NC*PP floats (5.06 MB)
    float*  ppr   = pla + (size_t)NC*PP;                // NC*PP floats
    double* grams = (double*)(ppr + (size_t)NC*PP);     // NC*361 doubles (byte off divisible by 8)
    double* accum = grams + (size_t)NC*GS;              // 4 doubles

    // ws is re-poisoned 0xAA before every launch: zero gram+accum region
    hipMemsetAsync(grams, 0, ((size_t)NC*GS + 4)*sizeof(double), stream);

    int total = NC*PP;
    k_bce_pool<<<(total + 255)/256, 256, 0, stream>>>(logits, labels, pla, ppr, accum);
    k_gram<<<NC*NSTRIP*3, 192, 0, stream>>>(pla, ppr, grams);
    k_solve<<<NC, 128, 0, stream>>>(grams, accum);
    k_final<<<1, 64, 0, stream>>>(accum, out);
}